// Round 7
// baseline (196.226 us; speedup 1.0000x reference)
//
#include <hip/hip_runtime.h>
#include <cstddef>
#include <cstdint>

#define DIM   512
#define NSEQ  1024
#define NB    4
#define LOG2E 1.44269504f
#define TBL8  528392  // (2*128+1)^2 * 8 heads

typedef unsigned short u16;
typedef short bf16x8 __attribute__((ext_vector_type(8)));
typedef _Float16 half8v __attribute__((ext_vector_type(8)));
typedef float f32x4  __attribute__((ext_vector_type(4)));

#define MFMA(a, b, c)  __builtin_amdgcn_mfma_f32_16x16x32_bf16(a, b, c, 0, 0, 0)
#define MFMAH(a, b, c) __builtin_amdgcn_mfma_f32_16x16x32_f16(a, b, c, 0, 0, 0)

// RNE fp32 -> bf16 split: x ~= hi + lo (error ~2^-18 * |x|)
__device__ inline void split2(float x, u16& h, u16& l) {
  unsigned u = __float_as_uint(x);
  unsigned hb = (u + 0x7fffu + ((u >> 16) & 1u)) >> 16;
  float fh = __uint_as_float(hb << 16);
  float r = x - fh;
  unsigned v = __float_as_uint(r);
  unsigned lb = (v + 0x7fffu + ((v >> 16) & 1u)) >> 16;
  h = (u16)hb; l = (u16)lb;
}

__device__ inline uint2 pack4(const u16 a[4]) {
  return make_uint2((unsigned)a[0] | ((unsigned)a[1] << 16),
                    (unsigned)a[2] | ((unsigned)a[3] << 16));
}

__device__ inline u16 f2h(float x) {
  _Float16 h = (_Float16)x;
  u16 r; __builtin_memcpy(&r, &h, 2);
  return r;
}
__device__ inline float h2f(u16 b) {
  _Float16 h; __builtin_memcpy(&h, &b, 2);
  return (float)h;
}
__device__ inline unsigned pkh2(float a, float b) {
  return (unsigned)f2h(a) | ((unsigned)f2h(b) << 16);
}

// fp32 [rows][512] -> u16 [rows][1024] (hi plane | lo plane)
__device__ inline void split_body(const float* __restrict__ in,
                                  u16* __restrict__ out, int e4) {
  const int e = e4 * 4;
  const int m = e >> 9, c = e & 511;
  const float4 v = *(const float4*)(in + e);
  u16 h[4], l[4];
  split2(v.x, h[0], l[0]); split2(v.y, h[1], l[1]);
  split2(v.z, h[2], l[2]); split2(v.w, h[3], l[3]);
  u16* o = out + (size_t)m * 1024 + c;
  *(uint2*)o = pack4(h);
  *(uint2*)(o + 512) = pack4(l);
}

#define GLDS(g, l)                                                        \
  __builtin_amdgcn_global_load_lds(                                       \
      (const __attribute__((address_space(1))) void*)(g),                 \
      (__attribute__((address_space(3))) void*)(l), 16, 0, 0)

// =====================================================================
// prep_split: weight + x split, PLUS rpe table fp32 -> fp16*LOG2E
// (one 16-B row of 8 heads per idx — single-uint4 gather downstream).
// blocks [0,1024): W{q,k,v,p}; [1024,5120): x_q / x_kv;
// [5120,5379): rpe16 conversion.  (round-4-verified layout)
// =====================================================================
__global__ __launch_bounds__(256) void prep_split(
    const float* __restrict__ wq, const float* __restrict__ wk,
    const float* __restrict__ wv, const float* __restrict__ wp,
    const float* __restrict__ xq, const float* __restrict__ xkv,
    const float* __restrict__ rpe,
    u16* __restrict__ w2, u16* __restrict__ xq2, u16* __restrict__ xkv2,
    u16* __restrict__ rpe16) {
  const int id = blockIdx.x;
  const int t = threadIdx.x;
  if (id < 1024) {
    const int y = id >> 8;
    const float* src = (y == 0) ? wq : (y == 1) ? wk : (y == 2) ? wv : wp;
    split_body(src, w2 + (size_t)y * 524288, (id & 255) * 256 + t);
  } else if (id < 5120) {
    const int e = id - 1024;
    const int y = e >> 11;
    split_body(y ? xkv : xq, y ? xkv2 : xq2, (e & 2047) * 256 + t);
  } else {
    const int e = (id - 5120) * 2048 + t * 8;
    if (e < TBL8) {
      const float4 f0 = *(const float4*)(rpe + e);
      const float4 f1 = *(const float4*)(rpe + e + 4);
      uint4 o;
      o.x = pkh2(f0.x * LOG2E, f0.y * LOG2E);
      o.y = pkh2(f0.z * LOG2E, f0.w * LOG2E);
      o.z = pkh2(f1.x * LOG2E, f1.y * LOG2E);
      o.w = pkh2(f1.z * LOG2E, f1.w * LOG2E);
      *(uint4*)(rpe16 + e) = o;
    }
  }
}

// =====================================================================
// Split-bf16 MFMA GEMM, 128x128 tile, BK=32, double-buffered, ONE
// barrier per K-iter (r13-verified). LDS rows 64 u16 [hi|lo], XOR-8.
// OUT_MODE: 3 fp16 [m][512] (scaled); 4 fp16 vt [(b*512+col)*1024+k].
// =====================================================================
template <int OUT_MODE>
__device__ __forceinline__ void gemm_db(
    u16 (*__restrict__ As)[8192], u16 (*__restrict__ Bs)[8192],
    const u16* __restrict__ A2, const u16* __restrict__ B2,
    const float* __restrict__ bias, void* __restrict__ outp,
    float scale, int m0, int n0) {
  const int tid = threadIdx.x;
  const int lane = tid & 63, w = tid >> 6;
  const int wm = (w & 1) * 64, wn = (w >> 1) * 64;
  const int lr8 = lane >> 3;
  const int scc = (lane & 7) ^ lr8;
  const int colA = ((scc & 3) * 8) + ((scc >> 2) * 512);

  const int fr = lane & 15, kq = lane >> 4, fx = fr & 7;
  int aoh[4], aol[4], boh[4], bol[4];
#pragma unroll
  for (int i = 0; i < 4; ++i) {
    const int ra = (wm + i * 16 + fr) * 64;
    aoh[i] = ra + ((kq ^ fx)) * 8;
    aol[i] = ra + (((4 + kq) ^ fx)) * 8;
    const int rb = (wn + i * 16 + fr) * 64;
    boh[i] = rb + ((kq ^ fx)) * 8;
    bol[i] = rb + (((4 + kq) ^ fx)) * 8;
  }

  auto stage = [&](int it, int p) {
    const int k0 = it * 32;
#pragma unroll
    for (int i = 0; i < 4; ++i) {
      const int rA = m0 + w * 32 + i * 8 + lr8;
      GLDS(A2 + (size_t)rA * 1024 + colA + k0,
           (char*)As[p] + (w * 32 + i * 8) * 128);
      const int rB = n0 + w * 32 + i * 8 + lr8;
      GLDS(B2 + (size_t)rB * 1024 + colA + k0,
           (char*)Bs[p] + (w * 32 + i * 8) * 128);
    }
  };

  f32x4 acc[4][4] = {};
  stage(0, 0);
  for (int it = 0; it < 16; ++it) {
    const int p = it & 1;
    __syncthreads();
    if (it + 1 < 16) stage(it + 1, p ^ 1);
    const u16* Ab = As[p];
    const u16* Bb = Bs[p];
    bf16x8 ah[4], al[4], bh[4], bl[4];
#pragma unroll
    for (int i = 0; i < 4; ++i) {
      ah[i] = *(const bf16x8*)(Ab + aoh[i]);
      al[i] = *(const bf16x8*)(Ab + aol[i]);
      bh[i] = *(const bf16x8*)(Bb + boh[i]);
      bl[i] = *(const bf16x8*)(Bb + bol[i]);
    }
#pragma unroll
    for (int i = 0; i < 4; ++i)
#pragma unroll
      for (int j = 0; j < 4; ++j) {
        acc[i][j] = MFMA(al[i], bh[j], acc[i][j]);
        acc[i][j] = MFMA(ah[i], bl[j], acc[i][j]);
        acc[i][j] = MFMA(ah[i], bh[j], acc[i][j]);
      }
  }

  const int er = (lane >> 4) * 4, ec = lane & 15;
#pragma unroll
  for (int i = 0; i < 4; ++i)
#pragma unroll
    for (int j = 0; j < 4; ++j) {
      const int row = m0 + wm + i * 16 + er;
      const int col = n0 + wn + j * 16 + ec;
      const float bv = bias[col];
      if (OUT_MODE == 4) {
        u16 hf[4];
#pragma unroll
        for (int r = 0; r < 4; ++r) hf[r] = f2h((acc[i][j][r] + bv) * scale);
        const int bb = row >> 10, kk = row & 1023;
        *(uint2*)((u16*)outp + ((size_t)(bb * 512 + col)) * 1024 + kk) =
            pack4(hf);
      } else {
#pragma unroll
        for (int r = 0; r < 4; ++r)
          ((u16*)outp)[(size_t)(row + r) * 512 + col] =
              f2h((acc[i][j][r] + bv) * scale);
      }
    }
}

// =====================================================================
// Fused QKV GEMMs + rpe gather in ONE dispatch (round-4-verified):
// ids [0,384): gemm_db z-slices; [384,4480): rpe gather (single uint4
// gather per pair, direct coalesced u16 stores).
// =====================================================================
__global__ __launch_bounds__(256) void qkv_rpe(
    const u16* __restrict__ xq2, const u16* __restrict__ xkv2,
    const u16* __restrict__ w2, const float* __restrict__ bq,
    const float* __restrict__ bk, const float* __restrict__ bv,
    u16* __restrict__ q2f, u16* __restrict__ k2f, u16* __restrict__ vtf,
    const int* __restrict__ cq, const int* __restrict__ ck,
    const u16* __restrict__ rpe16, u16* __restrict__ biasT) {
  __shared__ __align__(16) u16 As[2][8192], Bs[2][8192];
  const int id = blockIdx.x;
  const int t = threadIdx.x;
  if (id < 384) {
    const int z = id >> 7, rem = id & 127;
    const int m0 = (rem & 31) * 128, n0 = (rem >> 5) * 128;
    if (z == 0)
      gemm_db<3>(As, Bs, xq2, w2, bq, q2f, 0.125f * LOG2E, m0, n0);
    else if (z == 1)
      gemm_db<3>(As, Bs, xkv2, w2 + 524288, bk, k2f, 1.0f, m0, n0);
    else
      gemm_db<4>(As, Bs, xkv2, w2 + 2 * 524288, bv, vtf, 1.0f, m0, n0);
  } else {
    // rpe gather: biasT[b][h][k][q] fp16*log2e from rpe16 (uint4/pair).
    const int e = id - 384;
    const int q0 = (e & 15) * 64, k0 = ((e >> 4) & 63) * 16, b = e >> 10;
    const int qn = t & 63, kb = t >> 6;
    const int2 cqv = ((const int2*)cq)[b * NSEQ + q0 + qn];
    uint4 g[4];
#pragma unroll
    for (int j = 0; j < 4; ++j) {
      const int k = kb * 4 + j;
      const int2 ckv = ((const int2*)ck)[b * NSEQ + k0 + k];
      const int r0 = min(max(cqv.x - ckv.x + 128, 0), 256);
      const int r1 = min(max(cqv.y - ckv.y + 128, 0), 256);
      g[j] = *(const uint4*)(rpe16 + (size_t)(r0 * 257 + r1) * 8);
    }
    u16* dst0 = biasT + ((size_t)(b * 8) << 20) + q0 + qn;
#pragma unroll
    for (int j = 0; j < 4; ++j) {
      u16* dst = dst0 + ((size_t)(k0 + kb * 4 + j) << 10);
      const unsigned ww[4] = {g[j].x, g[j].y, g[j].z, g[j].w};
#pragma unroll
      for (int p2 = 0; p2 < 4; ++p2) {
        dst[(size_t)(2 * p2 + 0) << 20] = (u16)(ww[p2] & 0xffffu);
        dst[(size_t)(2 * p2 + 1) << 20] = (u16)(ww[p2] >> 16);
      }
    }
  }
}

// =====================================================================
// Output projection: 128x64 tile (r11-verified gemm128 body), fp32 out.
// Grid (32, 8) m-major = 256 blocks (2x the 128x128 grid's fill).
// =====================================================================
__global__ __launch_bounds__(256, 3) void gemm_out(
    const u16* __restrict__ A2, const u16* __restrict__ B2,
    const float* __restrict__ bias, float* __restrict__ out) {
  __shared__ __align__(16) u16 Ah[8192], Al[8192], Bh[4096], Bl[4096];
  const int m0 = blockIdx.x * 128, n0 = blockIdx.y * 64;
  const int tid = threadIdx.x;
  const int lane = tid & 63, w = tid >> 6;
  const int wm = (w & 1) * 64, wn = (w >> 1) * 32;
  const int lr = lane >> 3;
  const int scc = (lane & 7) ^ lr;

  const u16* gA = A2 + (size_t)(m0 + w * 32 + lr) * 1024 + scc * 8;
  const u16* gB = B2 + (size_t)(n0 + w * 16 + lr) * 1024 + scc * 8;
  char* lAh = (char*)Ah + w * 4096;  char* lAl = (char*)Al + w * 4096;
  char* lBh = (char*)Bh + w * 2048;  char* lBl = (char*)Bl + w * 2048;

  const int fr = lane & 15, kq = lane >> 4, fx = fr & 7;
  int aoff[2][4], boff[2][2];
#pragma unroll
  for (int s = 0; s < 2; ++s) {
#pragma unroll
    for (int i = 0; i < 4; ++i)
      aoff[s][i] = (wm + i * 16 + fr) * 64 + (((s * 4 + kq) ^ fx)) * 8;
#pragma unroll
    for (int j = 0; j < 2; ++j)
      boff[s][j] = (wn + j * 16 + fr) * 64 + (((s * 4 + kq) ^ fx)) * 8;
  }

  f32x4 acc[4][2] = {};
  for (int k0 = 0; k0 < 512; k0 += 64) {
    __syncthreads();
#pragma unroll
    for (int i = 0; i < 4; ++i) {
      GLDS(gA + (size_t)i * 8192 + k0, lAh + i * 1024);
      GLDS(gA + (size_t)i * 8192 + 512 + k0, lAl + i * 1024);
    }
#pragma unroll
    for (int i = 0; i < 2; ++i) {
      GLDS(gB + (size_t)i * 8192 + k0, lBh + i * 1024);
      GLDS(gB + (size_t)i * 8192 + 512 + k0, lBl + i * 1024);
    }
    __syncthreads();
#pragma unroll
    for (int s = 0; s < 2; ++s) {
      bf16x8 ah[4], al[4], bh[2], bl[2];
#pragma unroll
      for (int i = 0; i < 4; ++i) {
        ah[i] = *(const bf16x8*)(Ah + aoff[s][i]);
        al[i] = *(const bf16x8*)(Al + aoff[s][i]);
      }
#pragma unroll
      for (int j = 0; j < 2; ++j) {
        bh[j] = *(const bf16x8*)(Bh + boff[s][j]);
        bl[j] = *(const bf16x8*)(Bl + boff[s][j]);
      }
#pragma unroll
      for (int i = 0; i < 4; ++i)
#pragma unroll
        for (int j = 0; j < 2; ++j) {
          acc[i][j] = MFMA(al[i], bh[j], acc[i][j]);
          acc[i][j] = MFMA(ah[i], bl[j], acc[i][j]);
          acc[i][j] = MFMA(ah[i], bh[j], acc[i][j]);
        }
    }
  }

  const int er = (lane >> 4) * 4, ec = lane & 15;
#pragma unroll
  for (int i = 0; i < 4; ++i)
#pragma unroll
    for (int j = 0; j < 2; ++j) {
      const int row = m0 + wm + i * 16 + er;
      const int col = n0 + wn + j * 16 + ec;
      const float bv = bias[col];
#pragma unroll
      for (int r = 0; r < 4; ++r)
        out[(size_t)(row + r) * 512 + col] = acc[i][j][r] + bv;
    }
}

// =====================================================================
// fp16 MFMA differential flash attention (r16 body — 46.4 us) with
// r18: XCD-aware 1D grid decode. Each XCD (blockIdx.x & 7) owns 2 of
// the 16 (b,hp) combos, so its private L2 holds only ~1.5 MB of
// K/V/Q slices (vs ~8 MB thrash under linear round-robin dispatch).
// biasT (64 MB) streams regardless.
// =====================================================================
__global__ __launch_bounds__(512) void attn_f16(
    const u16* __restrict__ q2f, const u16* __restrict__ k2f,
    const u16* __restrict__ vtf, const float* __restrict__ amap,
    const float* __restrict__ lq1, const float* __restrict__ lk1,
    const float* __restrict__ lq2, const float* __restrict__ lk2,
    const u16* __restrict__ biasT, u16* __restrict__ xo) {
  __shared__ __align__(16) u16 KsL[2][2][4096];
  __shared__ __align__(16) u16 VtL[2][2][4096];
  __shared__ float2 mls[2][2][2][16];
  __shared__ float l2s[32];
  __shared__ float lam_s;

  const int tid = threadIdx.x;
  const int lane = tid & 63, w = tid >> 6;
  const int kg = w >> 2, h = (w >> 1) & 1, qs = w & 1;
  const int wl = w & 3;
  // XCD-aware decode: n = xcd_slot(3b) | combo_half(1b)+qtile(5b)
  const int n = blockIdx.x;
  const int xs = n & 7, jj = n >> 3;
  const int c = xs * 2 + (jj >> 5);   // (b,hp) combo 0..15
  const int hp = c & 3, b = c >> 2;
  const int q0 = (jj & 31) * 32;
  const int head = hp + 4 * h;
  const int lq = lane & 15, lg = lane >> 4;
  const int q = qs * 16 + lq;
  const size_t qrow = (size_t)(b * NSEQ + q0 + q);

  if (tid < 64) {
    float p1 = lq1[hp * 64 + tid] * lk1[hp * 64 + tid];
    float p2 = lq2[hp * 64 + tid] * lk2[hp * 64 + tid];
#pragma unroll
    for (int m = 32; m >= 1; m >>= 1) {
      p1 += __shfl_xor(p1, m, 64);
      p2 += __shfl_xor(p2, m, 64);
    }
    if (tid == 0) lam_s = __expf(p1) - __expf(p2) + 0.8f;
  }

  const float alpha = amap[qrow];

  half8v Qf[2];
#pragma unroll
  for (int ks = 0; ks < 2; ++ks)
    Qf[ks] = *(const half8v*)(q2f + qrow * 512 + head * 64 + ks * 32 + lg * 8);

  f32x4 Ya[4] = {};
  f32x4 Yb[4] = {};
  float m_run = -1e30f, l_run = 0.0f;

  const int lr = lane >> 3;
  const int lc = (lane & 7) ^ lr;
  const int cw = wl * 2;

  auto stage = [&](int it, int p) {
    const int kbase = kg * 512 + it * 32;
#pragma unroll
    for (int i = 0; i < 2; ++i) {
      const int c2 = cw + i;
      const int row = c2 * 8 + lr;
      const int sh = row >> 5, k = row & 31;
      const u16* src = k2f + (size_t)(b * NSEQ + kbase + k) * 512 +
                       (hp + 4 * sh) * 64 + lc * 8;
      GLDS(src, (char*)KsL[kg][p] + c2 * 1024);
    }
#pragma unroll
    for (int i = 0; i < 2; ++i) {
      const int c2 = cw + i;
      const int d = c2 * 8 + lr;
      const int hv = lc >> 2, kc = lc & 3;
      const u16* src = vtf + (size_t)(b * 512 + (hp + 4 * hv) * 64 + d) * 1024 +
                       kbase + kc * 8;
      GLDS(src, (char*)VtL[kg][p] + c2 * 1024);
    }
  };

  const u16* bT = biasT + ((size_t)(b * 8 + head) << 20) + q0 + q;

  auto ldbias = [&](int it, u16* r) {
    const u16* bt = bT + (size_t)(kg * 512 + it * 32) * 1024;
#pragma unroll
    for (int kt = 0; kt < 2; ++kt)
#pragma unroll
      for (int rr = 0; rr < 4; ++rr)
        r[kt * 4 + rr] = bt[(size_t)(kt * 16 + lg * 4 + rr) * 1024];
  };

  stage(0, 0);
  u16 rb[8];
  ldbias(0, rb);

  for (int it = 0; it < 16; ++it) {
    const int p = it & 1;
    __syncthreads();
    u16 rbn[8];
    if (it + 1 < 16) {
      stage(it + 1, p ^ 1);
      ldbias(it + 1, rbn);  // prefetch: drained by next barrier
    }

    const u16* Kb = KsL[kg][p];
    // bias as MFMA C-init: s = K*Q + bias, no post-add.
    f32x4 st[2];
#pragma unroll
    for (int kt = 0; kt < 2; ++kt)
#pragma unroll
      for (int r = 0; r < 4; ++r) st[kt][r] = h2f(rb[kt * 4 + r]);
    __builtin_amdgcn_s_setprio(1);
#pragma unroll
    for (int kt = 0; kt < 2; ++kt) {
      const int krow = kt * 16 + lq;
      const int rx = krow & 7;
#pragma unroll
      for (int ks = 0; ks < 2; ++ks) {
        const int phys = (ks * 4 + lg) ^ rx;
        const half8v kf = *(const half8v*)(Kb + (h * 32 + krow) * 64 + phys * 8);
        st[kt] = MFMAH(kf, Qf[ks], st[kt]);
      }
    }
    __builtin_amdgcn_s_setprio(0);

    float mx = -1e30f;
#pragma unroll
    for (int kt = 0; kt < 2; ++kt)
#pragma unroll
      for (int r = 0; r < 4; ++r) mx = fmaxf(mx, st[kt][r]);
    mx = fmaxf(mx, __shfl_xor(mx, 16, 64));
    mx = fmaxf(mx, __shfl_xor(mx, 32, 64));
    // T13 defer-rescale: only rescale when some q-row's max grew by >8
    // (log2 units). Otherwise keep m_run; P bounded by 2^8, fp16-safe.
    if (__any(mx > m_run + 8.0f)) {
      const float mnew = fmaxf(m_run, mx);
      const float a = exp2f(m_run - mnew);
      m_run = mnew;
      l_run *= a;
#pragma unroll
      for (int dt = 0; dt < 4; ++dt) Ya[dt] *= a;
      if (h == 1) {
#pragma unroll
        for (int dt = 0; dt < 4; ++dt) Yb[dt] *= a;
      }
    }
    float pr[2][4], ps = 0.0f;
#pragma unroll
    for (int kt = 0; kt < 2; ++kt)
#pragma unroll
      for (int r = 0; r < 4; ++r) {
        pr[kt][r] = exp2f(st[kt][r] - m_run);
        ps += pr[kt][r];
      }
    ps += __shfl_xor(ps, 16, 64);
    ps += __shfl_xor(ps, 32, 64);
    l_run += ps;

    const unsigned a0 = pkh2(pr[0][0], pr[0][1]);
    const unsigned a1 = pkh2(pr[0][2], pr[0][3]);
    const unsigned b0 = pkh2(pr[1][0], pr[1][1]);
    const unsigned b1 = pkh2(pr[1][2], pr[1][3]);
    const int srcA = lq + ((lg & 1) << 5);
    const unsigned A0 = __shfl((int)a0, srcA),      A1 = __shfl((int)a1, srcA);
    const unsigned B0 = __shfl((int)b0, srcA),      B1 = __shfl((int)b1, srcA);
    const unsigned C0 = __shfl((int)a0, srcA + 16), C1 = __shfl((int)a1, srcA + 16);
    const unsigned D0 = __shfl((int)b0, srcA + 16), D1 = __shfl((int)b1, srcA + 16);
    const bool t2 = lg >= 2;
    const uint4 Pu = make_uint4(t2 ? B0 : A0, t2 ? B1 : A1,
                                t2 ? D0 : C0, t2 ? D1 : C1);
    half8v pb;
    __builtin_memcpy(&pb, &Pu, 16);

    const u16* Vb = VtL[kg][p];
    __builtin_amdgcn_s_setprio(1);
    if (h == 0) {
#pragma unroll
      for (int dt = 0; dt < 4; ++dt) {
        const int d = dt * 16 + lq;
        const half8v v1 = *(const half8v*)(Vb + d * 64 + ((lg ^ (d & 7))) * 8);
        Ya[dt] = MFMAH(v1, pb, Ya[dt]);
      }
    } else {
#pragma unroll
      for (int dt = 0; dt < 4; ++dt) {
        const int d = dt * 16 + lq;
        const int dx = d & 7;
        const half8v v1 = *(const half8v*)(Vb + d * 64 + ((lg ^ dx)) * 8);
        Yb[dt] = MFMAH(v1, pb, Yb[dt]);
        const half8v v2 = *(const half8v*)(Vb + d * 64 + (((4 + lg) ^ dx)) * 8);
        Ya[dt] = MFMAH(v2, pb, Ya[dt]);
      }
    }
    __builtin_amdgcn_s_setprio(0);

    if (it + 1 < 16) {
#pragma unroll
      for (int z = 0; z < 8; ++z) rb[z] = rbn[z];
    }
  }

  float* mY = (float*)KsL;
  float* mB = (float*)VtL;
  __syncthreads();
  if (lane < 16) mls[kg][h][qs][lane] = make_float2(m_run, l_run);
  if (kg == 1) {
#pragma unroll
    for (int dt = 0; dt < 4; ++dt)
#pragma unroll
      for (int r = 0; r < 4; ++r)
        mY[((h * 2 + qs) * 64 + lane) * 16 + dt * 4 + r] = Ya[dt][r];
    if (h == 1) {
#pragma unroll
      for (int dt = 0; dt < 4; ++dt)
#pragma unroll
        for (int r = 0; r < 4; ++r)
          mB[(qs * 64 + lane) * 16 + dt * 4 + r] = Yb[dt][r];
    }
  }
  __syncthreads();
  float l_tot = l_run;
  if (kg == 0) {
    const float2 o = mls[1][h][qs][lq];
    const float mm = fmaxf(m_run, o.x);
    const float s0 = exp2f(m_run - mm);
    const float s1 = exp2f(o.x - mm);
    l_tot = l_run * s0 + o.y * s1;
    const float* sY = mY + ((h * 2 + qs) * 64 + lane) * 16;
#pragma unroll
    for (int dt = 0; dt < 4; ++dt)
#pragma unroll
      for (int r = 0; r < 4; ++r)
        Ya[dt][r] = Ya[dt][r] * s0 + sY[dt * 4 + r] * s1;
    if (h == 1) {
      const float* sB = mB + (qs * 64 + lane) * 16;
#pragma unroll
      for (int dt = 0; dt < 4; ++dt)
#pragma unroll
        for (int r = 0; r < 4; ++r)
          Yb[dt][r] = Yb[dt][r] * s0 + sB[dt * 4 + r] * s1;
    }
  }

  __syncthreads();
  float* y2x = (float*)KsL;
  if (kg == 0 && h == 1) {
    if (lane < 16) l2s[qs * 16 + lane] = l_tot;
#pragma unroll
    for (int dt = 0; dt < 4; ++dt)
#pragma unroll
      for (int r = 0; r < 4; ++r)
        y2x[(qs * 64 + lane) * 16 + dt * 4 + r] = Yb[dt][r];
  }
  __syncthreads();
  if (kg == 0 && h == 1) {
    const float inv2 = 1.0f / l_tot;
#pragma unroll
    for (int dt = 0; dt < 4; ++dt) {
      u16 hh[4], ll[4];
#pragma unroll
      for (int r = 0; r < 4; ++r) split2(Ya[dt][r] * inv2, hh[r], ll[r]);
      u16* o = xo + qrow * 1024 + (hp + 4) * 64 + dt * 16 + lg * 4;
      *(uint2*)o = pack4(hh);
      *(uint2*)(o + 512) = pack4(ll);
    }
  } else if (kg == 0 && h == 0) {
    const float inv1 = 1.0f / l_tot;
    const float inv2 = 1.0f / l2s[qs * 16 + lq];
    const float c1 = (1.0f + alpha) * inv1;
    const float c2 = alpha * lam_s * inv2;
#pragma unroll
    for (int dt = 0; dt < 4; ++dt) {
      u16 hh[4], ll[4];
#pragma unroll
      for (int r = 0; r < 4; ++r) {
        const float y2 = y2x[(qs * 64 + lane) * 16 + dt * 4 + r];
        split2(c1 * Ya[dt][r] - c2 * y2, hh[r], ll[r]);
      }
      u16* o = xo + qrow * 1024 + hp * 64 + dt * 16 + lg * 4;
      *(uint2*)o = pack4(hh);
      *(uint2*)(o + 512) = pack4(ll);
    }
  }
}

// =====================================================================
extern "C" void kernel_launch(void* const* d_in, const int* in_sizes, int n_in,
                              void* d_out, int out_size, void* d_ws, size_t ws_size,
                              hipStream_t stream) {
  const float* x_q   = (const float*)d_in[0];
  const float* x_kv  = (const float*)d_in[1];
  const int*   c_q   = (const int*)d_in[2];
  const int*   c_k   = (const int*)d_in[3];
  const float* alpha = (const float*)d_in[4];
  const float* Wq    = (const float*)d_in[5];
  const float* bq    = (const float*)d_in[6];
  const float* Wk    = (const float*)d_in[7];
  const float* bk    = (const float*)d_in[8];
  const float* Wv    = (const float*)d_in[9];
  const float* bv    = (const float*)d_in[10];
  const float* lq1   = (const float*)d_in[11];
  const float* lk1   = (const float*)d_in[12];
  const float* lq2   = (const float*)d_in[13];
  const float* lk2   = (const float*)d_in[14];
  const float* rpe   = (const float*)d_in[15];
  const float* Wp    = (const float*)d_in[16];
  const float* bp    = (const float*)d_in[17];

  // ws: w2[0,4) | xq2[4,12) (xa aliases after gemm) | q2f[12,16)
  //     | k2f[16,20) | vtf[20,24) | rpe16[24,25.1) | biasT[28,92).
  // d_out holds xkv2 until gemm_out overwrites it with the result.
  u16* w2    = (u16*)d_ws;
  u16* xq2   = (u16*)((char*)d_ws + (4u << 20));
  u16* q2f   = (u16*)((char*)d_ws + (12u << 20));
  u16* k2f   = (u16*)((char*)d_ws + (16u << 20));
  u16* vtf   = (u16*)((char*)d_ws + (20u << 20));
  u16* rpe16 = (u16*)((char*)d_ws + (24u << 20));
  u16* xa    = xq2;              // alias: xq2 dead after qkv_rpe
  u16* biasT = (u16*)((char*)d_ws + (28u << 20));
  u16* xkv2  = (u16*)d_out;

  prep_split<<<5379, 256, 0, stream>>>(Wq, Wk, Wv, Wp, x_q, x_kv, rpe,
                                       w2, xq2, xkv2, rpe16);
  qkv_rpe<<<4480, 256, 0, stream>>>(xq2, xkv2, w2, bq, bk, bv,
                                    q2f, k2f, vtf, c_q, c_k, rpe16, biasT);
  attn_f16<<<512, 512, 0, stream>>>(
      q2f, k2f, vtf, alpha, lq1, lk1, lq2, lk2, biasT, xa);
  gemm_out<<<dim3(32, 8), 256, 0, stream>>>(xa, w2 + 3 * 524288, bp,
                                            (float*)d_out);
}

// Round 8
// 192.890 us; speedup vs baseline: 1.0173x; 1.0173x over previous
//
#include <hip/hip_runtime.h>
#include <cstddef>
#include <cstdint>

#define DIM   512
#define NSEQ  1024
#define NB    4
#define LOG2E 1.44269504f
#define TBL8  528392  // (2*128+1)^2 * 8 heads

typedef unsigned short u16;
typedef short bf16x8 __attribute__((ext_vector_type(8)));
typedef _Float16 half8v __attribute__((ext_vector_type(8)));
typedef float f32x4  __attribute__((ext_vector_type(4)));

#define MFMA(a, b, c)  __builtin_amdgcn_mfma_f32_16x16x32_bf16(a, b, c, 0, 0, 0)
#define MFMAH(a, b, c) __builtin_amdgcn_mfma_f32_16x16x32_f16(a, b, c, 0, 0, 0)

// RNE fp32 -> bf16 split: x ~= hi + lo (error ~2^-18 * |x|)
__device__ inline void split2(float x, u16& h, u16& l) {
  unsigned u = __float_as_uint(x);
  unsigned hb = (u + 0x7fffu + ((u >> 16) & 1u)) >> 16;
  float fh = __uint_as_float(hb << 16);
  float r = x - fh;
  unsigned v = __float_as_uint(r);
  unsigned lb = (v + 0x7fffu + ((v >> 16) & 1u)) >> 16;
  h = (u16)hb; l = (u16)lb;
}

__device__ inline uint2 pack4(const u16 a[4]) {
  return make_uint2((unsigned)a[0] | ((unsigned)a[1] << 16),
                    (unsigned)a[2] | ((unsigned)a[3] << 16));
}

__device__ inline u16 f2h(float x) {
  _Float16 h = (_Float16)x;
  u16 r; __builtin_memcpy(&r, &h, 2);
  return r;
}
__device__ inline float h2f(u16 b) {
  _Float16 h; __builtin_memcpy(&h, &b, 2);
  return (float)h;
}
__device__ inline unsigned pkh2(float a, float b) {
  return (unsigned)f2h(a) | ((unsigned)f2h(b) << 16);
}

// fp32 [rows][512] -> u16 [rows][1024] (hi plane | lo plane)
__device__ inline void split_body(const float* __restrict__ in,
                                  u16* __restrict__ out, int e4) {
  const int e = e4 * 4;
  const int m = e >> 9, c = e & 511;
  const float4 v = *(const float4*)(in + e);
  u16 h[4], l[4];
  split2(v.x, h[0], l[0]); split2(v.y, h[1], l[1]);
  split2(v.z, h[2], l[2]); split2(v.w, h[3], l[3]);
  u16* o = out + (size_t)m * 1024 + c;
  *(uint2*)o = pack4(h);
  *(uint2*)(o + 512) = pack4(l);
}

#define GLDS(g, l)                                                        \
  __builtin_amdgcn_global_load_lds(                                       \
      (const __attribute__((address_space(1))) void*)(g),                 \
      (__attribute__((address_space(3))) void*)(l), 16, 0, 0)

// =====================================================================
// prep_split: weight + x split, PLUS rpe table fp32 -> fp16*LOG2E
// (one 16-B row of 8 heads per idx — single-uint4 gather downstream).
// blocks [0,1024): W{q,k,v,p}; [1024,5120): x_q / x_kv;
// [5120,5379): rpe16 conversion.  (round-4-verified layout)
// =====================================================================
__global__ __launch_bounds__(256) void prep_split(
    const float* __restrict__ wq, const float* __restrict__ wk,
    const float* __restrict__ wv, const float* __restrict__ wp,
    const float* __restrict__ xq, const float* __restrict__ xkv,
    const float* __restrict__ rpe,
    u16* __restrict__ w2, u16* __restrict__ xq2, u16* __restrict__ xkv2,
    u16* __restrict__ rpe16) {
  const int id = blockIdx.x;
  const int t = threadIdx.x;
  if (id < 1024) {
    const int y = id >> 8;
    const float* src = (y == 0) ? wq : (y == 1) ? wk : (y == 2) ? wv : wp;
    split_body(src, w2 + (size_t)y * 524288, (id & 255) * 256 + t);
  } else if (id < 5120) {
    const int e = id - 1024;
    const int y = e >> 11;
    split_body(y ? xkv : xq, y ? xkv2 : xq2, (e & 2047) * 256 + t);
  } else {
    const int e = (id - 5120) * 2048 + t * 8;
    if (e < TBL8) {
      const float4 f0 = *(const float4*)(rpe + e);
      const float4 f1 = *(const float4*)(rpe + e + 4);
      uint4 o;
      o.x = pkh2(f0.x * LOG2E, f0.y * LOG2E);
      o.y = pkh2(f0.z * LOG2E, f0.w * LOG2E);
      o.z = pkh2(f1.x * LOG2E, f1.y * LOG2E);
      o.w = pkh2(f1.z * LOG2E, f1.w * LOG2E);
      *(uint4*)(rpe16 + e) = o;
    }
  }
}

// =====================================================================
// Split-bf16 MFMA GEMM, 128x64 tile, BK=64 (gemm_out-verified body),
// 48 KB LDS (vs 128x128's 64 KB) => 3 blocks/CU in the fused dispatch.
// OUT_MODE: 3 fp16 [m][512] (scaled); 4 fp16 vt [(b*512+col)*1024+k].
// =====================================================================
template <int OUT_MODE>
__device__ __forceinline__ void gemm64(
    u16* __restrict__ Ah, u16* __restrict__ Al,
    u16* __restrict__ Bh, u16* __restrict__ Bl,
    const u16* __restrict__ A2, const u16* __restrict__ B2,
    const float* __restrict__ bias, void* __restrict__ outp,
    float scale, int m0, int n0) {
  const int tid = threadIdx.x;
  const int lane = tid & 63, w = tid >> 6;
  const int wm = (w & 1) * 64, wn = (w >> 1) * 32;
  const int lr = lane >> 3;
  const int scc = (lane & 7) ^ lr;

  const u16* gA = A2 + (size_t)(m0 + w * 32 + lr) * 1024 + scc * 8;
  const u16* gB = B2 + (size_t)(n0 + w * 16 + lr) * 1024 + scc * 8;
  char* lAh = (char*)Ah + w * 4096;  char* lAl = (char*)Al + w * 4096;
  char* lBh = (char*)Bh + w * 2048;  char* lBl = (char*)Bl + w * 2048;

  const int fr = lane & 15, kq = lane >> 4, fx = fr & 7;
  int aoff[2][4], boff[2][2];
#pragma unroll
  for (int s = 0; s < 2; ++s) {
#pragma unroll
    for (int i = 0; i < 4; ++i)
      aoff[s][i] = (wm + i * 16 + fr) * 64 + (((s * 4 + kq) ^ fx)) * 8;
#pragma unroll
    for (int j = 0; j < 2; ++j)
      boff[s][j] = (wn + j * 16 + fr) * 64 + (((s * 4 + kq) ^ fx)) * 8;
  }

  f32x4 acc[4][2] = {};
  for (int k0 = 0; k0 < 512; k0 += 64) {
    __syncthreads();
#pragma unroll
    for (int i = 0; i < 4; ++i) {
      GLDS(gA + (size_t)i * 8192 + k0, lAh + i * 1024);
      GLDS(gA + (size_t)i * 8192 + 512 + k0, lAl + i * 1024);
    }
#pragma unroll
    for (int i = 0; i < 2; ++i) {
      GLDS(gB + (size_t)i * 8192 + k0, lBh + i * 1024);
      GLDS(gB + (size_t)i * 8192 + 512 + k0, lBl + i * 1024);
    }
    __syncthreads();
#pragma unroll
    for (int s = 0; s < 2; ++s) {
      bf16x8 ah[4], al[4], bh[2], bl[2];
#pragma unroll
      for (int i = 0; i < 4; ++i) {
        ah[i] = *(const bf16x8*)(Ah + aoff[s][i]);
        al[i] = *(const bf16x8*)(Al + aoff[s][i]);
      }
#pragma unroll
      for (int j = 0; j < 2; ++j) {
        bh[j] = *(const bf16x8*)(Bh + boff[s][j]);
        bl[j] = *(const bf16x8*)(Bl + boff[s][j]);
      }
#pragma unroll
      for (int i = 0; i < 4; ++i)
#pragma unroll
        for (int j = 0; j < 2; ++j) {
          acc[i][j] = MFMA(al[i], bh[j], acc[i][j]);
          acc[i][j] = MFMA(ah[i], bl[j], acc[i][j]);
          acc[i][j] = MFMA(ah[i], bh[j], acc[i][j]);
        }
    }
  }

  const int er = (lane >> 4) * 4, ec = lane & 15;
#pragma unroll
  for (int i = 0; i < 4; ++i)
#pragma unroll
    for (int j = 0; j < 2; ++j) {
      const int row = m0 + wm + i * 16 + er;
      const int col = n0 + wn + j * 16 + ec;
      const float bv = bias[col];
      if (OUT_MODE == 4) {
        u16 hf[4];
#pragma unroll
        for (int r = 0; r < 4; ++r) hf[r] = f2h((acc[i][j][r] + bv) * scale);
        const int bb = row >> 10, kk = row & 1023;
        *(uint2*)((u16*)outp + ((size_t)(bb * 512 + col)) * 1024 + kk) =
            pack4(hf);
      } else {
#pragma unroll
        for (int r = 0; r < 4; ++r)
          ((u16*)outp)[(size_t)(row + r) * 512 + col] =
              f2h((acc[i][j][r] + bv) * scale);
      }
    }
}

// =====================================================================
// Fused QKV GEMMs + rpe gather in ONE dispatch.
// r19: GEMM switched to the 48 KB 128x64 body => whole dispatch runs
// 3 blocks/CU (was 2 with the 64 KB 128x128 template) — +50% TLP for
// the 4096 latency-bound gather blocks AND +50% GEMM wave parallelism.
// ids [0,768): GEMM (z = id>>8, 32 m-tiles x 8 n-tiles);
// ids [768,4864): rpe gather (round-1-verified body).
// =====================================================================
__global__ __launch_bounds__(256) void qkv_rpe(
    const u16* __restrict__ xq2, const u16* __restrict__ xkv2,
    const u16* __restrict__ w2, const float* __restrict__ bq,
    const float* __restrict__ bk, const float* __restrict__ bv,
    u16* __restrict__ q2f, u16* __restrict__ k2f, u16* __restrict__ vtf,
    const int* __restrict__ cq, const int* __restrict__ ck,
    const u16* __restrict__ rpe16, u16* __restrict__ biasT) {
  __shared__ __align__(16) u16 Ah[8192], Al[8192], Bh[4096], Bl[4096];
  const int id = blockIdx.x;
  const int t = threadIdx.x;
  if (id < 768) {
    const int z = id >> 8, rem = id & 255;
    const int m0 = (rem & 31) * 128, n0 = (rem >> 5) * 64;
    if (z == 0)
      gemm64<3>(Ah, Al, Bh, Bl, xq2, w2, bq, q2f, 0.125f * LOG2E, m0, n0);
    else if (z == 1)
      gemm64<3>(Ah, Al, Bh, Bl, xkv2, w2 + 524288, bk, k2f, 1.0f, m0, n0);
    else
      gemm64<4>(Ah, Al, Bh, Bl, xkv2, w2 + 2 * 524288, bv, vtf, 1.0f, m0, n0);
  } else {
    // rpe gather: biasT[b][h][k][q] fp16*log2e from rpe16 (uint4/pair).
    const int e = id - 768;
    const int q0 = (e & 15) * 64, k0 = ((e >> 4) & 63) * 16, b = e >> 10;
    const int qn = t & 63, kb = t >> 6;
    const int2 cqv = ((const int2*)cq)[b * NSEQ + q0 + qn];
    uint4 g[4];
#pragma unroll
    for (int j = 0; j < 4; ++j) {
      const int k = kb * 4 + j;
      const int2 ckv = ((const int2*)ck)[b * NSEQ + k0 + k];
      const int r0 = min(max(cqv.x - ckv.x + 128, 0), 256);
      const int r1 = min(max(cqv.y - ckv.y + 128, 0), 256);
      g[j] = *(const uint4*)(rpe16 + (size_t)(r0 * 257 + r1) * 8);
    }
    u16* dst0 = biasT + ((size_t)(b * 8) << 20) + q0 + qn;
#pragma unroll
    for (int j = 0; j < 4; ++j) {
      u16* dst = dst0 + ((size_t)(k0 + kb * 4 + j) << 10);
      const unsigned ww[4] = {g[j].x, g[j].y, g[j].z, g[j].w};
#pragma unroll
      for (int p2 = 0; p2 < 4; ++p2) {
        dst[(size_t)(2 * p2 + 0) << 20] = (u16)(ww[p2] & 0xffffu);
        dst[(size_t)(2 * p2 + 1) << 20] = (u16)(ww[p2] >> 16);
      }
    }
  }
}

// =====================================================================
// Output projection: 128x64 tile (r11-verified gemm128 body), fp32 out.
// Grid (32, 8) m-major = 256 blocks (2x the 128x128 grid's fill).
// =====================================================================
__global__ __launch_bounds__(256, 3) void gemm_out(
    const u16* __restrict__ A2, const u16* __restrict__ B2,
    const float* __restrict__ bias, float* __restrict__ out) {
  __shared__ __align__(16) u16 Ah[8192], Al[8192], Bh[4096], Bl[4096];
  const int m0 = blockIdx.x * 128, n0 = blockIdx.y * 64;
  const int tid = threadIdx.x;
  const int lane = tid & 63, w = tid >> 6;
  const int wm = (w & 1) * 64, wn = (w >> 1) * 32;
  const int lr = lane >> 3;
  const int scc = (lane & 7) ^ lr;

  const u16* gA = A2 + (size_t)(m0 + w * 32 + lr) * 1024 + scc * 8;
  const u16* gB = B2 + (size_t)(n0 + w * 16 + lr) * 1024 + scc * 8;
  char* lAh = (char*)Ah + w * 4096;  char* lAl = (char*)Al + w * 4096;
  char* lBh = (char*)Bh + w * 2048;  char* lBl = (char*)Bl + w * 2048;

  const int fr = lane & 15, kq = lane >> 4, fx = fr & 7;
  int aoff[2][4], boff[2][2];
#pragma unroll
  for (int s = 0; s < 2; ++s) {
#pragma unroll
    for (int i = 0; i < 4; ++i)
      aoff[s][i] = (wm + i * 16 + fr) * 64 + (((s * 4 + kq) ^ fx)) * 8;
#pragma unroll
    for (int j = 0; j < 2; ++j)
      boff[s][j] = (wn + j * 16 + fr) * 64 + (((s * 4 + kq) ^ fx)) * 8;
  }

  f32x4 acc[4][2] = {};
  for (int k0 = 0; k0 < 512; k0 += 64) {
    __syncthreads();
#pragma unroll
    for (int i = 0; i < 4; ++i) {
      GLDS(gA + (size_t)i * 8192 + k0, lAh + i * 1024);
      GLDS(gA + (size_t)i * 8192 + 512 + k0, lAl + i * 1024);
    }
#pragma unroll
    for (int i = 0; i < 2; ++i) {
      GLDS(gB + (size_t)i * 8192 + k0, lBh + i * 1024);
      GLDS(gB + (size_t)i * 8192 + 512 + k0, lBl + i * 1024);
    }
    __syncthreads();
#pragma unroll
    for (int s = 0; s < 2; ++s) {
      bf16x8 ah[4], al[4], bh[2], bl[2];
#pragma unroll
      for (int i = 0; i < 4; ++i) {
        ah[i] = *(const bf16x8*)(Ah + aoff[s][i]);
        al[i] = *(const bf16x8*)(Al + aoff[s][i]);
      }
#pragma unroll
      for (int j = 0; j < 2; ++j) {
        bh[j] = *(const bf16x8*)(Bh + boff[s][j]);
        bl[j] = *(const bf16x8*)(Bl + boff[s][j]);
      }
#pragma unroll
      for (int i = 0; i < 4; ++i)
#pragma unroll
        for (int j = 0; j < 2; ++j) {
          acc[i][j] = MFMA(al[i], bh[j], acc[i][j]);
          acc[i][j] = MFMA(ah[i], bl[j], acc[i][j]);
          acc[i][j] = MFMA(ah[i], bh[j], acc[i][j]);
        }
    }
  }

  const int er = (lane >> 4) * 4, ec = lane & 15;
#pragma unroll
  for (int i = 0; i < 4; ++i)
#pragma unroll
    for (int j = 0; j < 2; ++j) {
      const int row = m0 + wm + i * 16 + er;
      const int col = n0 + wn + j * 16 + ec;
      const float bv = bias[col];
#pragma unroll
      for (int r = 0; r < 4; ++r)
        out[(size_t)(row + r) * 512 + col] = acc[i][j][r] + bv;
    }
}

// =====================================================================
// fp16 MFMA differential flash attention (r16 body + r18 XCD decode).
// Each XCD (blockIdx.x & 7) owns 2 of the 16 (b,hp) combos => private
// L2 holds ~1.5 MB of K/V/Q slices (vs ~8 MB round-robin thrash).
// =====================================================================
__global__ __launch_bounds__(512) void attn_f16(
    const u16* __restrict__ q2f, const u16* __restrict__ k2f,
    const u16* __restrict__ vtf, const float* __restrict__ amap,
    const float* __restrict__ lq1, const float* __restrict__ lk1,
    const float* __restrict__ lq2, const float* __restrict__ lk2,
    const u16* __restrict__ biasT, u16* __restrict__ xo) {
  __shared__ __align__(16) u16 KsL[2][2][4096];
  __shared__ __align__(16) u16 VtL[2][2][4096];
  __shared__ float2 mls[2][2][2][16];
  __shared__ float l2s[32];
  __shared__ float lam_s;

  const int tid = threadIdx.x;
  const int lane = tid & 63, w = tid >> 6;
  const int kg = w >> 2, h = (w >> 1) & 1, qs = w & 1;
  const int wl = w & 3;
  // XCD-aware decode: n = xcd_slot(3b) | combo_half(1b)+qtile(5b)
  const int n = blockIdx.x;
  const int xs = n & 7, jj = n >> 3;
  const int c = xs * 2 + (jj >> 5);   // (b,hp) combo 0..15
  const int hp = c & 3, b = c >> 2;
  const int q0 = (jj & 31) * 32;
  const int head = hp + 4 * h;
  const int lq = lane & 15, lg = lane >> 4;
  const int q = qs * 16 + lq;
  const size_t qrow = (size_t)(b * NSEQ + q0 + q);

  if (tid < 64) {
    float p1 = lq1[hp * 64 + tid] * lk1[hp * 64 + tid];
    float p2 = lq2[hp * 64 + tid] * lk2[hp * 64 + tid];
#pragma unroll
    for (int m = 32; m >= 1; m >>= 1) {
      p1 += __shfl_xor(p1, m, 64);
      p2 += __shfl_xor(p2, m, 64);
    }
    if (tid == 0) lam_s = __expf(p1) - __expf(p2) + 0.8f;
  }

  const float alpha = amap[qrow];

  half8v Qf[2];
#pragma unroll
  for (int ks = 0; ks < 2; ++ks)
    Qf[ks] = *(const half8v*)(q2f + qrow * 512 + head * 64 + ks * 32 + lg * 8);

  f32x4 Ya[4] = {};
  f32x4 Yb[4] = {};
  float m_run = -1e30f, l_run = 0.0f;

  const int lr = lane >> 3;
  const int lc = (lane & 7) ^ lr;
  const int cw = wl * 2;

  auto stage = [&](int it, int p) {
    const int kbase = kg * 512 + it * 32;
#pragma unroll
    for (int i = 0; i < 2; ++i) {
      const int c2 = cw + i;
      const int row = c2 * 8 + lr;
      const int sh = row >> 5, k = row & 31;
      const u16* src = k2f + (size_t)(b * NSEQ + kbase + k) * 512 +
                       (hp + 4 * sh) * 64 + lc * 8;
      GLDS(src, (char*)KsL[kg][p] + c2 * 1024);
    }
#pragma unroll
    for (int i = 0; i < 2; ++i) {
      const int c2 = cw + i;
      const int d = c2 * 8 + lr;
      const int hv = lc >> 2, kc = lc & 3;
      const u16* src = vtf + (size_t)(b * 512 + (hp + 4 * hv) * 64 + d) * 1024 +
                       kbase + kc * 8;
      GLDS(src, (char*)VtL[kg][p] + c2 * 1024);
    }
  };

  const u16* bT = biasT + ((size_t)(b * 8 + head) << 20) + q0 + q;

  auto ldbias = [&](int it, u16* r) {
    const u16* bt = bT + (size_t)(kg * 512 + it * 32) * 1024;
#pragma unroll
    for (int kt = 0; kt < 2; ++kt)
#pragma unroll
      for (int rr = 0; rr < 4; ++rr)
        r[kt * 4 + rr] = bt[(size_t)(kt * 16 + lg * 4 + rr) * 1024];
  };

  stage(0, 0);
  u16 rb[8];
  ldbias(0, rb);

  for (int it = 0; it < 16; ++it) {
    const int p = it & 1;
    __syncthreads();
    u16 rbn[8];
    if (it + 1 < 16) {
      stage(it + 1, p ^ 1);
      ldbias(it + 1, rbn);  // prefetch: drained by next barrier
    }

    const u16* Kb = KsL[kg][p];
    // bias as MFMA C-init: s = K*Q + bias, no post-add.
    f32x4 st[2];
#pragma unroll
    for (int kt = 0; kt < 2; ++kt)
#pragma unroll
      for (int r = 0; r < 4; ++r) st[kt][r] = h2f(rb[kt * 4 + r]);
    __builtin_amdgcn_s_setprio(1);
#pragma unroll
    for (int kt = 0; kt < 2; ++kt) {
      const int krow = kt * 16 + lq;
      const int rx = krow & 7;
#pragma unroll
      for (int ks = 0; ks < 2; ++ks) {
        const int phys = (ks * 4 + lg) ^ rx;
        const half8v kf = *(const half8v*)(Kb + (h * 32 + krow) * 64 + phys * 8);
        st[kt] = MFMAH(kf, Qf[ks], st[kt]);
      }
    }
    __builtin_amdgcn_s_setprio(0);

    float mx = -1e30f;
#pragma unroll
    for (int kt = 0; kt < 2; ++kt)
#pragma unroll
      for (int r = 0; r < 4; ++r) mx = fmaxf(mx, st[kt][r]);
    mx = fmaxf(mx, __shfl_xor(mx, 16, 64));
    mx = fmaxf(mx, __shfl_xor(mx, 32, 64));
    // T13 defer-rescale: only rescale when some q-row's max grew by >8
    // (log2 units). Otherwise keep m_run; P bounded by 2^8, fp16-safe.
    if (__any(mx > m_run + 8.0f)) {
      const float mnew = fmaxf(m_run, mx);
      const float a = exp2f(m_run - mnew);
      m_run = mnew;
      l_run *= a;
#pragma unroll
      for (int dt = 0; dt < 4; ++dt) Ya[dt] *= a;
      if (h == 1) {
#pragma unroll
        for (int dt = 0; dt < 4; ++dt) Yb[dt] *= a;
      }
    }
    float pr[2][4], ps = 0.0f;
#pragma unroll
    for (int kt = 0; kt < 2; ++kt)
#pragma unroll
      for (int r = 0; r < 4; ++r) {
        pr[kt][r] = exp2f(st[kt][r] - m_run);
        ps += pr[kt][r];
      }
    ps += __shfl_xor(ps, 16, 64);
    ps += __shfl_xor(ps, 32, 64);
    l_run += ps;

    const unsigned a0 = pkh2(pr[0][0], pr[0][1]);
    const unsigned a1 = pkh2(pr[0][2], pr[0][3]);
    const unsigned b0 = pkh2(pr[1][0], pr[1][1]);
    const unsigned b1 = pkh2(pr[1][2], pr[1][3]);
    const int srcA = lq + ((lg & 1) << 5);
    const unsigned A0 = __shfl((int)a0, srcA),      A1 = __shfl((int)a1, srcA);
    const unsigned B0 = __shfl((int)b0, srcA),      B1 = __shfl((int)b1, srcA);
    const unsigned C0 = __shfl((int)a0, srcA + 16), C1 = __shfl((int)a1, srcA + 16);
    const unsigned D0 = __shfl((int)b0, srcA + 16), D1 = __shfl((int)b1, srcA + 16);
    const bool t2 = lg >= 2;
    const uint4 Pu = make_uint4(t2 ? B0 : A0, t2 ? B1 : A1,
                                t2 ? D0 : C0, t2 ? D1 : C1);
    half8v pb;
    __builtin_memcpy(&pb, &Pu, 16);

    const u16* Vb = VtL[kg][p];
    __builtin_amdgcn_s_setprio(1);
    if (h == 0) {
#pragma unroll
      for (int dt = 0; dt < 4; ++dt) {
        const int d = dt * 16 + lq;
        const half8v v1 = *(const half8v*)(Vb + d * 64 + ((lg ^ (d & 7))) * 8);
        Ya[dt] = MFMAH(v1, pb, Ya[dt]);
      }
    } else {
#pragma unroll
      for (int dt = 0; dt < 4; ++dt) {
        const int d = dt * 16 + lq;
        const int dx = d & 7;
        const half8v v1 = *(const half8v*)(Vb + d * 64 + ((lg ^ dx)) * 8);
        Yb[dt] = MFMAH(v1, pb, Yb[dt]);
        const half8v v2 = *(const half8v*)(Vb + d * 64 + (((4 + lg) ^ dx)) * 8);
        Ya[dt] = MFMAH(v2, pb, Ya[dt]);
      }
    }
    __builtin_amdgcn_s_setprio(0);

    if (it + 1 < 16) {
#pragma unroll
      for (int z = 0; z < 8; ++z) rb[z] = rbn[z];
    }
  }

  float* mY = (float*)KsL;
  float* mB = (float*)VtL;
  __syncthreads();
  if (lane < 16) mls[kg][h][qs][lane] = make_float2(m_run, l_run);
  if (kg == 1) {
#pragma unroll
    for (int dt = 0; dt < 4; ++dt)
#pragma unroll
      for (int r = 0; r < 4; ++r)
        mY[((h * 2 + qs) * 64 + lane) * 16 + dt * 4 + r] = Ya[dt][r];
    if (h == 1) {
#pragma unroll
      for (int dt = 0; dt < 4; ++dt)
#pragma unroll
        for (int r = 0; r < 4; ++r)
          mB[(qs * 64 + lane) * 16 + dt * 4 + r] = Yb[dt][r];
    }
  }
  __syncthreads();
  float l_tot = l_run;
  if (kg == 0) {
    const float2 o = mls[1][h][qs][lq];
    const float mm = fmaxf(m_run, o.x);
    const float s0 = exp2f(m_run - mm);
    const float s1 = exp2f(o.x - mm);
    l_tot = l_run * s0 + o.y * s1;
    const float* sY = mY + ((h * 2 + qs) * 64 + lane) * 16;
#pragma unroll
    for (int dt = 0; dt < 4; ++dt)
#pragma unroll
      for (int r = 0; r < 4; ++r)
        Ya[dt][r] = Ya[dt][r] * s0 + sY[dt * 4 + r] * s1;
    if (h == 1) {
      const float* sB = mB + (qs * 64 + lane) * 16;
#pragma unroll
      for (int dt = 0; dt < 4; ++dt)
#pragma unroll
        for (int r = 0; r < 4; ++r)
          Yb[dt][r] = Yb[dt][r] * s0 + sB[dt * 4 + r] * s1;
    }
  }

  __syncthreads();
  float* y2x = (float*)KsL;
  if (kg == 0 && h == 1) {
    if (lane < 16) l2s[qs * 16 + lane] = l_tot;
#pragma unroll
    for (int dt = 0; dt < 4; ++dt)
#pragma unroll
      for (int r = 0; r < 4; ++r)
        y2x[(qs * 64 + lane) * 16 + dt * 4 + r] = Yb[dt][r];
  }
  __syncthreads();
  if (kg == 0 && h == 1) {
    const float inv2 = 1.0f / l_tot;
#pragma unroll
    for (int dt = 0; dt < 4; ++dt) {
      u16 hh[4], ll[4];
#pragma unroll
      for (int r = 0; r < 4; ++r) split2(Ya[dt][r] * inv2, hh[r], ll[r]);
      u16* o = xo + qrow * 1024 + (hp + 4) * 64 + dt * 16 + lg * 4;
      *(uint2*)o = pack4(hh);
      *(uint2*)(o + 512) = pack4(ll);
    }
  } else if (kg == 0 && h == 0) {
    const float inv1 = 1.0f / l_tot;
    const float inv2 = 1.0f / l2s[qs * 16 + lq];
    const float c1 = (1.0f + alpha) * inv1;
    const float c2 = alpha * lam_s * inv2;
#pragma unroll
    for (int dt = 0; dt < 4; ++dt) {
      u16 hh[4], ll[4];
#pragma unroll
      for (int r = 0; r < 4; ++r) {
        const float y2 = y2x[(qs * 64 + lane) * 16 + dt * 4 + r];
        split2(c1 * Ya[dt][r] - c2 * y2, hh[r], ll[r]);
      }
      u16* o = xo + qrow * 1024 + hp * 64 + dt * 16 + lg * 4;
      *(uint2*)o = pack4(hh);
      *(uint2*)(o + 512) = pack4(ll);
    }
  }
}

// =====================================================================
extern "C" void kernel_launch(void* const* d_in, const int* in_sizes, int n_in,
                              void* d_out, int out_size, void* d_ws, size_t ws_size,
                              hipStream_t stream) {
  const float* x_q   = (const float*)d_in[0];
  const float* x_kv  = (const float*)d_in[1];
  const int*   c_q   = (const int*)d_in[2];
  const int*   c_k   = (const int*)d_in[3];
  const float* alpha = (const float*)d_in[4];
  const float* Wq    = (const float*)d_in[5];
  const float* bq    = (const float*)d_in[6];
  const float* Wk    = (const float*)d_in[7];
  const float* bk    = (const float*)d_in[8];
  const float* Wv    = (const float*)d_in[9];
  const float* bv    = (const float*)d_in[10];
  const float* lq1   = (const float*)d_in[11];
  const float* lk1   = (const float*)d_in[12];
  const float* lq2   = (const float*)d_in[13];
  const float* lk2   = (const float*)d_in[14];
  const float* rpe   = (const float*)d_in[15];
  const float* Wp    = (const float*)d_in[16];
  const float* bp    = (const float*)d_in[17];

  // ws: w2[0,4) | xq2[4,12) (xa aliases after gemm) | q2f[12,16)
  //     | k2f[16,20) | vtf[20,24) | rpe16[24,25.1) | biasT[28,92).
  // d_out holds xkv2 until gemm_out overwrites it with the result.
  u16* w2    = (u16*)d_ws;
  u16* xq2   = (u16*)((char*)d_ws + (4u << 20));
  u16* q2f   = (u16*)((char*)d_ws + (12u << 20));
  u16* k2f   = (u16*)((char*)d_ws + (16u << 20));
  u16* vtf   = (u16*)((char*)d_ws + (20u << 20));
  u16* rpe16 = (u16*)((char*)d_ws + (24u << 20));
  u16* xa    = xq2;              // alias: xq2 dead after qkv_rpe
  u16* biasT = (u16*)((char*)d_ws + (28u << 20));
  u16* xkv2  = (u16*)d_out;

  prep_split<<<5379, 256, 0, stream>>>(Wq, Wk, Wv, Wp, x_q, x_kv, rpe,
                                       w2, xq2, xkv2, rpe16);
  qkv_rpe<<<4864, 256, 0, stream>>>(xq2, xkv2, w2, bq, bk, bv,
                                    q2f, k2f, vtf, c_q, c_k, rpe16, biasT);
  attn_f16<<<512, 512, 0, stream>>>(
      q2f, k2f, vtf, alpha, lq1, lk1, lq2, lk2, biasT, xa);
  gemm_out<<<dim3(32, 8), 256, 0, stream>>>(xa, w2 + 3 * 524288, bp,
                                            (float*)d_out);
}

// Round 9
// 184.192 us; speedup vs baseline: 1.0653x; 1.0472x over previous
//
#include <hip/hip_runtime.h>
#include <cstddef>
#include <cstdint>

#define DIM   512
#define NSEQ  1024
#define NB    4
#define LOG2E 1.44269504f
#define TBL8  528392  // (2*128+1)^2 * 8 heads

typedef unsigned short u16;
typedef short bf16x8 __attribute__((ext_vector_type(8)));
typedef _Float16 half8v __attribute__((ext_vector_type(8)));
typedef float f32x4  __attribute__((ext_vector_type(4)));

#define MFMA(a, b, c)  __builtin_amdgcn_mfma_f32_16x16x32_bf16(a, b, c, 0, 0, 0)
#define MFMAH(a, b, c) __builtin_amdgcn_mfma_f32_16x16x32_f16(a, b, c, 0, 0, 0)

// RNE fp32 -> bf16 split: x ~= hi + lo (error ~2^-18 * |x|)
__device__ inline void split2(float x, u16& h, u16& l) {
  unsigned u = __float_as_uint(x);
  unsigned hb = (u + 0x7fffu + ((u >> 16) & 1u)) >> 16;
  float fh = __uint_as_float(hb << 16);
  float r = x - fh;
  unsigned v = __float_as_uint(r);
  unsigned lb = (v + 0x7fffu + ((v >> 16) & 1u)) >> 16;
  h = (u16)hb; l = (u16)lb;
}

__device__ inline uint2 pack4(const u16 a[4]) {
  return make_uint2((unsigned)a[0] | ((unsigned)a[1] << 16),
                    (unsigned)a[2] | ((unsigned)a[3] << 16));
}

__device__ inline u16 f2h(float x) {
  _Float16 h = (_Float16)x;
  u16 r; __builtin_memcpy(&r, &h, 2);
  return r;
}
__device__ inline float h2f(u16 b) {
  _Float16 h; __builtin_memcpy(&h, &b, 2);
  return (float)h;
}
__device__ inline unsigned pkh2(float a, float b) {
  return (unsigned)f2h(a) | ((unsigned)f2h(b) << 16);
}

// fp32 [rows][512] -> u16 [rows][1024] (hi plane | lo plane)
__device__ inline void split_body(const float* __restrict__ in,
                                  u16* __restrict__ out, int e4) {
  const int e = e4 * 4;
  const int m = e >> 9, c = e & 511;
  const float4 v = *(const float4*)(in + e);
  u16 h[4], l[4];
  split2(v.x, h[0], l[0]); split2(v.y, h[1], l[1]);
  split2(v.z, h[2], l[2]); split2(v.w, h[3], l[3]);
  u16* o = out + (size_t)m * 1024 + c;
  *(uint2*)o = pack4(h);
  *(uint2*)(o + 512) = pack4(l);
}

#define GLDS(g, l)                                                        \
  __builtin_amdgcn_global_load_lds(                                       \
      (const __attribute__((address_space(1))) void*)(g),                 \
      (__attribute__((address_space(3))) void*)(l), 16, 0, 0)

// =====================================================================
// prep_split: weight + x split, PLUS rpe table fp32 -> fp16*LOG2E
// (one 16-B row of 8 heads per idx — single-uint4 gather downstream).
// blocks [0,1024): W{q,k,v,p}; [1024,5120): x_q / x_kv;
// [5120,5379): rpe16 conversion.  (round-4-verified layout)
// =====================================================================
__global__ __launch_bounds__(256) void prep_split(
    const float* __restrict__ wq, const float* __restrict__ wk,
    const float* __restrict__ wv, const float* __restrict__ wp,
    const float* __restrict__ xq, const float* __restrict__ xkv,
    const float* __restrict__ rpe,
    u16* __restrict__ w2, u16* __restrict__ xq2, u16* __restrict__ xkv2,
    u16* __restrict__ rpe16) {
  const int id = blockIdx.x;
  const int t = threadIdx.x;
  if (id < 1024) {
    const int y = id >> 8;
    const float* src = (y == 0) ? wq : (y == 1) ? wk : (y == 2) ? wv : wp;
    split_body(src, w2 + (size_t)y * 524288, (id & 255) * 256 + t);
  } else if (id < 5120) {
    const int e = id - 1024;
    const int y = e >> 11;
    split_body(y ? xkv : xq, y ? xkv2 : xq2, (e & 2047) * 256 + t);
  } else {
    const int e = (id - 5120) * 2048 + t * 8;
    if (e < TBL8) {
      const float4 f0 = *(const float4*)(rpe + e);
      const float4 f1 = *(const float4*)(rpe + e + 4);
      uint4 o;
      o.x = pkh2(f0.x * LOG2E, f0.y * LOG2E);
      o.y = pkh2(f0.z * LOG2E, f0.w * LOG2E);
      o.z = pkh2(f1.x * LOG2E, f1.y * LOG2E);
      o.w = pkh2(f1.z * LOG2E, f1.w * LOG2E);
      *(uint4*)(rpe16 + e) = o;
    }
  }
}

// =====================================================================
// Split-bf16 MFMA GEMM, 128x64 tile, BK=64 (gemm_out-verified body),
// 48 KB LDS (vs 128x128's 64 KB) => 3 blocks/CU in the fused dispatch.
// OUT_MODE: 3 fp16 [m][512] (scaled); 4 fp16 vt [(b*512+col)*1024+k].
// =====================================================================
template <int OUT_MODE>
__device__ __forceinline__ void gemm64(
    u16* __restrict__ Ah, u16* __restrict__ Al,
    u16* __restrict__ Bh, u16* __restrict__ Bl,
    const u16* __restrict__ A2, const u16* __restrict__ B2,
    const float* __restrict__ bias, void* __restrict__ outp,
    float scale, int m0, int n0) {
  const int tid = threadIdx.x;
  const int lane = tid & 63, w = tid >> 6;
  const int wm = (w & 1) * 64, wn = (w >> 1) * 32;
  const int lr = lane >> 3;
  const int scc = (lane & 7) ^ lr;

  const u16* gA = A2 + (size_t)(m0 + w * 32 + lr) * 1024 + scc * 8;
  const u16* gB = B2 + (size_t)(n0 + w * 16 + lr) * 1024 + scc * 8;
  char* lAh = (char*)Ah + w * 4096;  char* lAl = (char*)Al + w * 4096;
  char* lBh = (char*)Bh + w * 2048;  char* lBl = (char*)Bl + w * 2048;

  const int fr = lane & 15, kq = lane >> 4, fx = fr & 7;
  int aoff[2][4], boff[2][2];
#pragma unroll
  for (int s = 0; s < 2; ++s) {
#pragma unroll
    for (int i = 0; i < 4; ++i)
      aoff[s][i] = (wm + i * 16 + fr) * 64 + (((s * 4 + kq) ^ fx)) * 8;
#pragma unroll
    for (int j = 0; j < 2; ++j)
      boff[s][j] = (wn + j * 16 + fr) * 64 + (((s * 4 + kq) ^ fx)) * 8;
  }

  f32x4 acc[4][2] = {};
  for (int k0 = 0; k0 < 512; k0 += 64) {
    __syncthreads();
#pragma unroll
    for (int i = 0; i < 4; ++i) {
      GLDS(gA + (size_t)i * 8192 + k0, lAh + i * 1024);
      GLDS(gA + (size_t)i * 8192 + 512 + k0, lAl + i * 1024);
    }
#pragma unroll
    for (int i = 0; i < 2; ++i) {
      GLDS(gB + (size_t)i * 8192 + k0, lBh + i * 1024);
      GLDS(gB + (size_t)i * 8192 + 512 + k0, lBl + i * 1024);
    }
    __syncthreads();
#pragma unroll
    for (int s = 0; s < 2; ++s) {
      bf16x8 ah[4], al[4], bh[2], bl[2];
#pragma unroll
      for (int i = 0; i < 4; ++i) {
        ah[i] = *(const bf16x8*)(Ah + aoff[s][i]);
        al[i] = *(const bf16x8*)(Al + aoff[s][i]);
      }
#pragma unroll
      for (int j = 0; j < 2; ++j) {
        bh[j] = *(const bf16x8*)(Bh + boff[s][j]);
        bl[j] = *(const bf16x8*)(Bl + boff[s][j]);
      }
#pragma unroll
      for (int i = 0; i < 4; ++i)
#pragma unroll
        for (int j = 0; j < 2; ++j) {
          acc[i][j] = MFMA(al[i], bh[j], acc[i][j]);
          acc[i][j] = MFMA(ah[i], bl[j], acc[i][j]);
          acc[i][j] = MFMA(ah[i], bh[j], acc[i][j]);
        }
    }
  }

  const int er = (lane >> 4) * 4, ec = lane & 15;
#pragma unroll
  for (int i = 0; i < 4; ++i)
#pragma unroll
    for (int j = 0; j < 2; ++j) {
      const int row = m0 + wm + i * 16 + er;
      const int col = n0 + wn + j * 16 + ec;
      const float bv = bias[col];
      if (OUT_MODE == 4) {
        u16 hf[4];
#pragma unroll
        for (int r = 0; r < 4; ++r) hf[r] = f2h((acc[i][j][r] + bv) * scale);
        const int bb = row >> 10, kk = row & 1023;
        *(uint2*)((u16*)outp + ((size_t)(bb * 512 + col)) * 1024 + kk) =
            pack4(hf);
      } else {
#pragma unroll
        for (int r = 0; r < 4; ++r)
          ((u16*)outp)[(size_t)(row + r) * 512 + col] =
              f2h((acc[i][j][r] + bv) * scale);
      }
    }
}

// =====================================================================
// Fused QKV GEMMs + rpe gather in ONE dispatch (r19-verified, 48 KB
// LDS => 3 blocks/CU). ids [0,768): GEMM; [768,4864): rpe gather.
// =====================================================================
__global__ __launch_bounds__(256) void qkv_rpe(
    const u16* __restrict__ xq2, const u16* __restrict__ xkv2,
    const u16* __restrict__ w2, const float* __restrict__ bq,
    const float* __restrict__ bk, const float* __restrict__ bv,
    u16* __restrict__ q2f, u16* __restrict__ k2f, u16* __restrict__ vtf,
    const int* __restrict__ cq, const int* __restrict__ ck,
    const u16* __restrict__ rpe16, u16* __restrict__ biasT) {
  __shared__ __align__(16) u16 Ah[8192], Al[8192], Bh[4096], Bl[4096];
  const int id = blockIdx.x;
  const int t = threadIdx.x;
  if (id < 768) {
    const int z = id >> 8, rem = id & 255;
    const int m0 = (rem & 31) * 128, n0 = (rem >> 5) * 64;
    if (z == 0)
      gemm64<3>(Ah, Al, Bh, Bl, xq2, w2, bq, q2f, 0.125f * LOG2E, m0, n0);
    else if (z == 1)
      gemm64<3>(Ah, Al, Bh, Bl, xkv2, w2 + 524288, bk, k2f, 1.0f, m0, n0);
    else
      gemm64<4>(Ah, Al, Bh, Bl, xkv2, w2 + 2 * 524288, bv, vtf, 1.0f, m0, n0);
  } else {
    // rpe gather: biasT[b][h][k][q] fp16*log2e from rpe16 (uint4/pair).
    const int e = id - 768;
    const int q0 = (e & 15) * 64, k0 = ((e >> 4) & 63) * 16, b = e >> 10;
    const int qn = t & 63, kb = t >> 6;
    const int2 cqv = ((const int2*)cq)[b * NSEQ + q0 + qn];
    uint4 g[4];
#pragma unroll
    for (int j = 0; j < 4; ++j) {
      const int k = kb * 4 + j;
      const int2 ckv = ((const int2*)ck)[b * NSEQ + k0 + k];
      const int r0 = min(max(cqv.x - ckv.x + 128, 0), 256);
      const int r1 = min(max(cqv.y - ckv.y + 128, 0), 256);
      g[j] = *(const uint4*)(rpe16 + (size_t)(r0 * 257 + r1) * 8);
    }
    u16* dst0 = biasT + ((size_t)(b * 8) << 20) + q0 + qn;
#pragma unroll
    for (int j = 0; j < 4; ++j) {
      u16* dst = dst0 + ((size_t)(k0 + kb * 4 + j) << 10);
      const unsigned ww[4] = {g[j].x, g[j].y, g[j].z, g[j].w};
#pragma unroll
      for (int p2 = 0; p2 < 4; ++p2) {
        dst[(size_t)(2 * p2 + 0) << 20] = (u16)(ww[p2] & 0xffffu);
        dst[(size_t)(2 * p2 + 1) << 20] = (u16)(ww[p2] >> 16);
      }
    }
  }
}

// =====================================================================
// Output projection: 128x64 tile (r11-verified gemm128 body), fp32 out.
// Grid (32, 8) m-major = 256 blocks (2x the 128x128 grid's fill).
// =====================================================================
__global__ __launch_bounds__(256, 3) void gemm_out(
    const u16* __restrict__ A2, const u16* __restrict__ B2,
    const float* __restrict__ bias, float* __restrict__ out) {
  __shared__ __align__(16) u16 Ah[8192], Al[8192], Bh[4096], Bl[4096];
  const int m0 = blockIdx.x * 128, n0 = blockIdx.y * 64;
  const int tid = threadIdx.x;
  const int lane = tid & 63, w = tid >> 6;
  const int wm = (w & 1) * 64, wn = (w >> 1) * 32;
  const int lr = lane >> 3;
  const int scc = (lane & 7) ^ lr;

  const u16* gA = A2 + (size_t)(m0 + w * 32 + lr) * 1024 + scc * 8;
  const u16* gB = B2 + (size_t)(n0 + w * 16 + lr) * 1024 + scc * 8;
  char* lAh = (char*)Ah + w * 4096;  char* lAl = (char*)Al + w * 4096;
  char* lBh = (char*)Bh + w * 2048;  char* lBl = (char*)Bl + w * 2048;

  const int fr = lane & 15, kq = lane >> 4, fx = fr & 7;
  int aoff[2][4], boff[2][2];
#pragma unroll
  for (int s = 0; s < 2; ++s) {
#pragma unroll
    for (int i = 0; i < 4; ++i)
      aoff[s][i] = (wm + i * 16 + fr) * 64 + (((s * 4 + kq) ^ fx)) * 8;
#pragma unroll
    for (int j = 0; j < 2; ++j)
      boff[s][j] = (wn + j * 16 + fr) * 64 + (((s * 4 + kq) ^ fx)) * 8;
  }

  f32x4 acc[4][2] = {};
  for (int k0 = 0; k0 < 512; k0 += 64) {
    __syncthreads();
#pragma unroll
    for (int i = 0; i < 4; ++i) {
      GLDS(gA + (size_t)i * 8192 + k0, lAh + i * 1024);
      GLDS(gA + (size_t)i * 8192 + 512 + k0, lAl + i * 1024);
    }
#pragma unroll
    for (int i = 0; i < 2; ++i) {
      GLDS(gB + (size_t)i * 8192 + k0, lBh + i * 1024);
      GLDS(gB + (size_t)i * 8192 + 512 + k0, lBl + i * 1024);
    }
    __syncthreads();
#pragma unroll
    for (int s = 0; s < 2; ++s) {
      bf16x8 ah[4], al[4], bh[2], bl[2];
#pragma unroll
      for (int i = 0; i < 4; ++i) {
        ah[i] = *(const bf16x8*)(Ah + aoff[s][i]);
        al[i] = *(const bf16x8*)(Al + aoff[s][i]);
      }
#pragma unroll
      for (int j = 0; j < 2; ++j) {
        bh[j] = *(const bf16x8*)(Bh + boff[s][j]);
        bl[j] = *(const bf16x8*)(Bl + boff[s][j]);
      }
#pragma unroll
      for (int i = 0; i < 4; ++i)
#pragma unroll
        for (int j = 0; j < 2; ++j) {
          acc[i][j] = MFMA(al[i], bh[j], acc[i][j]);
          acc[i][j] = MFMA(ah[i], bl[j], acc[i][j]);
          acc[i][j] = MFMA(ah[i], bh[j], acc[i][j]);
        }
    }
  }

  const int er = (lane >> 4) * 4, ec = lane & 15;
#pragma unroll
  for (int i = 0; i < 4; ++i)
#pragma unroll
    for (int j = 0; j < 2; ++j) {
      const int row = m0 + wm + i * 16 + er;
      const int col = n0 + wn + j * 16 + ec;
      const float bv = bias[col];
#pragma unroll
      for (int r = 0; r < 4; ++r)
        out[(size_t)(row + r) * 512 + col] = acc[i][j][r] + bv;
    }
}

// =====================================================================
// fp16 MFMA differential flash attention (r8 base + r20 chain trims):
// - defer-check via __any on PER-LANE max (row-max shfl reduce moved
//   inside the rare rescale branch; identical trigger + math).
// - l_run kept as per-lane partial; single shfl-reduce in epilogue
//   (rescale factor a is row-uniform, commutes with the reduction).
// - bias prefetch loads directly into rb after its last use (no copy).
// =====================================================================
__global__ __launch_bounds__(512) void attn_f16(
    const u16* __restrict__ q2f, const u16* __restrict__ k2f,
    const u16* __restrict__ vtf, const float* __restrict__ amap,
    const float* __restrict__ lq1, const float* __restrict__ lk1,
    const float* __restrict__ lq2, const float* __restrict__ lk2,
    const u16* __restrict__ biasT, u16* __restrict__ xo) {
  __shared__ __align__(16) u16 KsL[2][2][4096];
  __shared__ __align__(16) u16 VtL[2][2][4096];
  __shared__ float2 mls[2][2][2][16];
  __shared__ float l2s[32];
  __shared__ float lam_s;

  const int tid = threadIdx.x;
  const int lane = tid & 63, w = tid >> 6;
  const int kg = w >> 2, h = (w >> 1) & 1, qs = w & 1;
  const int wl = w & 3;
  // XCD-aware decode: n = xcd_slot(3b) | combo_half(1b)+qtile(5b)
  const int n = blockIdx.x;
  const int xs = n & 7, jj = n >> 3;
  const int c = xs * 2 + (jj >> 5);   // (b,hp) combo 0..15
  const int hp = c & 3, b = c >> 2;
  const int q0 = (jj & 31) * 32;
  const int head = hp + 4 * h;
  const int lq = lane & 15, lg = lane >> 4;
  const int q = qs * 16 + lq;
  const size_t qrow = (size_t)(b * NSEQ + q0 + q);

  if (tid < 64) {
    float p1 = lq1[hp * 64 + tid] * lk1[hp * 64 + tid];
    float p2 = lq2[hp * 64 + tid] * lk2[hp * 64 + tid];
#pragma unroll
    for (int m = 32; m >= 1; m >>= 1) {
      p1 += __shfl_xor(p1, m, 64);
      p2 += __shfl_xor(p2, m, 64);
    }
    if (tid == 0) lam_s = __expf(p1) - __expf(p2) + 0.8f;
  }

  const float alpha = amap[qrow];

  half8v Qf[2];
#pragma unroll
  for (int ks = 0; ks < 2; ++ks)
    Qf[ks] = *(const half8v*)(q2f + qrow * 512 + head * 64 + ks * 32 + lg * 8);

  f32x4 Ya[4] = {};
  f32x4 Yb[4] = {};
  float m_run = -1e30f, l_run = 0.0f;  // l_run: PER-LANE partial

  const int lr = lane >> 3;
  const int lc = (lane & 7) ^ lr;
  const int cw = wl * 2;

  auto stage = [&](int it, int p) {
    const int kbase = kg * 512 + it * 32;
#pragma unroll
    for (int i = 0; i < 2; ++i) {
      const int c2 = cw + i;
      const int row = c2 * 8 + lr;
      const int sh = row >> 5, k = row & 31;
      const u16* src = k2f + (size_t)(b * NSEQ + kbase + k) * 512 +
                       (hp + 4 * sh) * 64 + lc * 8;
      GLDS(src, (char*)KsL[kg][p] + c2 * 1024);
    }
#pragma unroll
    for (int i = 0; i < 2; ++i) {
      const int c2 = cw + i;
      const int d = c2 * 8 + lr;
      const int hv = lc >> 2, kc = lc & 3;
      const u16* src = vtf + (size_t)(b * 512 + (hp + 4 * hv) * 64 + d) * 1024 +
                       kbase + kc * 8;
      GLDS(src, (char*)VtL[kg][p] + c2 * 1024);
    }
  };

  const u16* bT = biasT + ((size_t)(b * 8 + head) << 20) + q0 + q;

  auto ldbias = [&](int it, u16* r) {
    const u16* bt = bT + (size_t)(kg * 512 + it * 32) * 1024;
#pragma unroll
    for (int kt = 0; kt < 2; ++kt)
#pragma unroll
      for (int rr = 0; rr < 4; ++rr)
        r[kt * 4 + rr] = bt[(size_t)(kt * 16 + lg * 4 + rr) * 1024];
  };

  stage(0, 0);
  u16 rb[8];
  ldbias(0, rb);

  for (int it = 0; it < 16; ++it) {
    const int p = it & 1;
    __syncthreads();
    if (it + 1 < 16) stage(it + 1, p ^ 1);

    // bias as MFMA C-init: s = K*Q + bias, no post-add.
    f32x4 st[2];
#pragma unroll
    for (int kt = 0; kt < 2; ++kt)
#pragma unroll
      for (int r = 0; r < 4; ++r) st[kt][r] = h2f(rb[kt * 4 + r]);
    if (it + 1 < 16) ldbias(it + 1, rb);  // prefetch after last use

    const u16* Kb = KsL[kg][p];
    __builtin_amdgcn_s_setprio(1);
#pragma unroll
    for (int kt = 0; kt < 2; ++kt) {
      const int krow = kt * 16 + lq;
      const int rx = krow & 7;
#pragma unroll
      for (int ks = 0; ks < 2; ++ks) {
        const int phys = (ks * 4 + lg) ^ rx;
        const half8v kf = *(const half8v*)(Kb + (h * 32 + krow) * 64 + phys * 8);
        st[kt] = MFMAH(kf, Qf[ks], st[kt]);
      }
    }
    __builtin_amdgcn_s_setprio(0);

    // per-lane max only; row reduce deferred into the rare branch.
    float mx = -1e30f;
#pragma unroll
    for (int kt = 0; kt < 2; ++kt)
#pragma unroll
      for (int r = 0; r < 4; ++r) mx = fmaxf(mx, st[kt][r]);
    // T13 defer-rescale: any lane's local max exceeding <=> its row
    // max exceeding, so trigger condition is identical.
    if (__any(mx > m_run + 8.0f)) {
      float rmx = fmaxf(mx, __shfl_xor(mx, 16, 64));
      rmx = fmaxf(rmx, __shfl_xor(rmx, 32, 64));
      const float mnew = fmaxf(m_run, rmx);
      const float a = exp2f(m_run - mnew);
      m_run = mnew;
      l_run *= a;
#pragma unroll
      for (int dt = 0; dt < 4; ++dt) Ya[dt] *= a;
      if (h == 1) {
#pragma unroll
        for (int dt = 0; dt < 4; ++dt) Yb[dt] *= a;
      }
    }
    float pr[2][4], ps = 0.0f;
#pragma unroll
    for (int kt = 0; kt < 2; ++kt)
#pragma unroll
      for (int r = 0; r < 4; ++r) {
        pr[kt][r] = exp2f(st[kt][r] - m_run);
        ps += pr[kt][r];
      }
    l_run += ps;  // per-lane partial; reduced once in epilogue

    const unsigned a0 = pkh2(pr[0][0], pr[0][1]);
    const unsigned a1 = pkh2(pr[0][2], pr[0][3]);
    const unsigned b0 = pkh2(pr[1][0], pr[1][1]);
    const unsigned b1 = pkh2(pr[1][2], pr[1][3]);
    const int srcA = lq + ((lg & 1) << 5);
    const unsigned A0 = __shfl((int)a0, srcA),      A1 = __shfl((int)a1, srcA);
    const unsigned B0 = __shfl((int)b0, srcA),      B1 = __shfl((int)b1, srcA);
    const unsigned C0 = __shfl((int)a0, srcA + 16), C1 = __shfl((int)a1, srcA + 16);
    const unsigned D0 = __shfl((int)b0, srcA + 16), D1 = __shfl((int)b1, srcA + 16);
    const bool t2 = lg >= 2;
    const uint4 Pu = make_uint4(t2 ? B0 : A0, t2 ? B1 : A1,
                                t2 ? D0 : C0, t2 ? D1 : C1);
    half8v pb;
    __builtin_memcpy(&pb, &Pu, 16);

    const u16* Vb = VtL[kg][p];
    __builtin_amdgcn_s_setprio(1);
    if (h == 0) {
#pragma unroll
      for (int dt = 0; dt < 4; ++dt) {
        const int d = dt * 16 + lq;
        const half8v v1 = *(const half8v*)(Vb + d * 64 + ((lg ^ (d & 7))) * 8);
        Ya[dt] = MFMAH(v1, pb, Ya[dt]);
      }
    } else {
#pragma unroll
      for (int dt = 0; dt < 4; ++dt) {
        const int d = dt * 16 + lq;
        const int dx = d & 7;
        const half8v v1 = *(const half8v*)(Vb + d * 64 + ((lg ^ dx)) * 8);
        Yb[dt] = MFMAH(v1, pb, Yb[dt]);
        const half8v v2 = *(const half8v*)(Vb + d * 64 + (((4 + lg) ^ dx)) * 8);
        Ya[dt] = MFMAH(v2, pb, Ya[dt]);
      }
    }
    __builtin_amdgcn_s_setprio(0);
  }

  // reduce the per-lane l partial to the row total (lanes lq, +16, +32,
  // +48 share a q-row).
  l_run += __shfl_xor(l_run, 16, 64);
  l_run += __shfl_xor(l_run, 32, 64);

  float* mY = (float*)KsL;
  float* mB = (float*)VtL;
  __syncthreads();
  if (lane < 16) mls[kg][h][qs][lane] = make_float2(m_run, l_run);
  if (kg == 1) {
#pragma unroll
    for (int dt = 0; dt < 4; ++dt)
#pragma unroll
      for (int r = 0; r < 4; ++r)
        mY[((h * 2 + qs) * 64 + lane) * 16 + dt * 4 + r] = Ya[dt][r];
    if (h == 1) {
#pragma unroll
      for (int dt = 0; dt < 4; ++dt)
#pragma unroll
        for (int r = 0; r < 4; ++r)
          mB[(qs * 64 + lane) * 16 + dt * 4 + r] = Yb[dt][r];
    }
  }
  __syncthreads();
  float l_tot = l_run;
  if (kg == 0) {
    const float2 o = mls[1][h][qs][lq];
    const float mm = fmaxf(m_run, o.x);
    const float s0 = exp2f(m_run - mm);
    const float s1 = exp2f(o.x - mm);
    l_tot = l_run * s0 + o.y * s1;
    const float* sY = mY + ((h * 2 + qs) * 64 + lane) * 16;
#pragma unroll
    for (int dt = 0; dt < 4; ++dt)
#pragma unroll
      for (int r = 0; r < 4; ++r)
        Ya[dt][r] = Ya[dt][r] * s0 + sY[dt * 4 + r] * s1;
    if (h == 1) {
      const float* sB = mB + (qs * 64 + lane) * 16;
#pragma unroll
      for (int dt = 0; dt < 4; ++dt)
#pragma unroll
        for (int r = 0; r < 4; ++r)
          Yb[dt][r] = Yb[dt][r] * s0 + sB[dt * 4 + r] * s1;
    }
  }

  __syncthreads();
  float* y2x = (float*)KsL;
  if (kg == 0 && h == 1) {
    if (lane < 16) l2s[qs * 16 + lane] = l_tot;
#pragma unroll
    for (int dt = 0; dt < 4; ++dt)
#pragma unroll
      for (int r = 0; r < 4; ++r)
        y2x[(qs * 64 + lane) * 16 + dt * 4 + r] = Yb[dt][r];
  }
  __syncthreads();
  if (kg == 0 && h == 1) {
    const float inv2 = 1.0f / l_tot;
#pragma unroll
    for (int dt = 0; dt < 4; ++dt) {
      u16 hh[4], ll[4];
#pragma unroll
      for (int r = 0; r < 4; ++r) split2(Ya[dt][r] * inv2, hh[r], ll[r]);
      u16* o = xo + qrow * 1024 + (hp + 4) * 64 + dt * 16 + lg * 4;
      *(uint2*)o = pack4(hh);
      *(uint2*)(o + 512) = pack4(ll);
    }
  } else if (kg == 0 && h == 0) {
    const float inv1 = 1.0f / l_tot;
    const float inv2 = 1.0f / l2s[qs * 16 + lq];
    const float c1 = (1.0f + alpha) * inv1;
    const float c2 = alpha * lam_s * inv2;
#pragma unroll
    for (int dt = 0; dt < 4; ++dt) {
      u16 hh[4], ll[4];
#pragma unroll
      for (int r = 0; r < 4; ++r) {
        const float y2 = y2x[(qs * 64 + lane) * 16 + dt * 4 + r];
        split2(c1 * Ya[dt][r] - c2 * y2, hh[r], ll[r]);
      }
      u16* o = xo + qrow * 1024 + hp * 64 + dt * 16 + lg * 4;
      *(uint2*)o = pack4(hh);
      *(uint2*)(o + 512) = pack4(ll);
    }
  }
}

// =====================================================================
extern "C" void kernel_launch(void* const* d_in, const int* in_sizes, int n_in,
                              void* d_out, int out_size, void* d_ws, size_t ws_size,
                              hipStream_t stream) {
  const float* x_q   = (const float*)d_in[0];
  const float* x_kv  = (const float*)d_in[1];
  const int*   c_q   = (const int*)d_in[2];
  const int*   c_k   = (const int*)d_in[3];
  const float* alpha = (const float*)d_in[4];
  const float* Wq    = (const float*)d_in[5];
  const float* bq    = (const float*)d_in[6];
  const float* Wk    = (const float*)d_in[7];
  const float* bk    = (const float*)d_in[8];
  const float* Wv    = (const float*)d_in[9];
  const float* bv    = (const float*)d_in[10];
  const float* lq1   = (const float*)d_in[11];
  const float* lk1   = (const float*)d_in[12];
  const float* lq2   = (const float*)d_in[13];
  const float* lk2   = (const float*)d_in[14];
  const float* rpe   = (const float*)d_in[15];
  const float* Wp    = (const float*)d_in[16];
  const float* bp    = (const float*)d_in[17];

  // ws: w2[0,4) | xq2[4,12) (xa aliases after gemm) | q2f[12,16)
  //     | k2f[16,20) | vtf[20,24) | rpe16[24,25.1) | biasT[28,92).
  // d_out holds xkv2 until gemm_out overwrites it with the result.
  u16* w2    = (u16*)d_ws;
  u16* xq2   = (u16*)((char*)d_ws + (4u << 20));
  u16* q2f   = (u16*)((char*)d_ws + (12u << 20));
  u16* k2f   = (u16*)((char*)d_ws + (16u << 20));
  u16* vtf   = (u16*)((char*)d_ws + (20u << 20));
  u16* rpe16 = (u16*)((char*)d_ws + (24u << 20));
  u16* xa    = xq2;              // alias: xq2 dead after qkv_rpe
  u16* biasT = (u16*)((char*)d_ws + (28u << 20));
  u16* xkv2  = (u16*)d_out;

  prep_split<<<5379, 256, 0, stream>>>(Wq, Wk, Wv, Wp, x_q, x_kv, rpe,
                                       w2, xq2, xkv2, rpe16);
  qkv_rpe<<<4864, 256, 0, stream>>>(xq2, xkv2, w2, bq, bk, bv,
                                    q2f, k2f, vtf, c_q, c_k, rpe16, biasT);
  attn_f16<<<512, 512, 0, stream>>>(
      q2f, k2f, vtf, alpha, lq1, lk1, lq2, lk2, biasT, xa);
  gemm_out<<<dim3(32, 8), 256, 0, stream>>>(xa, w2 + 3 * 524288, bp,
                                            (float*)d_out);
}